// Round 1
// baseline (224.804 us; speedup 1.0000x reference)
//
#include <hip/hip_runtime.h>
#include <math.h>
#include <limits.h>

// Homography warp + bilinear sampling, bit-faithful to the numpy reference:
//  - no FMA contraction anywhere (pragma) so products/sums round like np
//  - two IEEE divisions (not reciprocal-multiply)
//  - float->int32 emulates x86 cvttss2si (overflow -> INT_MIN -> clips to 0)
//  - weight/accumulate expression order identical to the reference

#define SMALL_F 1e-7f
#define EPS_F   1e-6f

__device__ __forceinline__ int cvt_f32_i32_x86(float f) {
    // x86 cvttss2si: values >= 2^31 (incl. +inf) give INT_MIN.
    // (int)f on gfx950 saturates low side to INT_MIN already, matching x86
    // for f <= -2^31. Only the high side differs.
    if (f >= 2147483648.0f) return INT_MIN;
    return (int)f;  // f is pre-floored, trunc == floor
}

__global__ void __launch_bounds__(256)
warp_bilinear_kernel(const float* __restrict__ src, const float* __restrict__ Hm,
                     float* __restrict__ out, int B, int h, int w) {
#pragma clang fp contract(off)
    int x = blockIdx.x * blockDim.x + threadIdx.x;
    int y = blockIdx.y;
    int b = blockIdx.z;
    if (x >= w) return;

    const float* Hb = Hm + (size_t)b * 9;   // block-uniform -> scalar loads
    float gx = (float)x;
    float gy = (float)y;

    // einsum('bij,jhw->bihw'): left-assoc over j = 0,1,2, no FMA
    float w0 = (Hb[0] * gx + Hb[1] * gy) + Hb[2];
    float w1 = (Hb[3] * gx + Hb[4] * gy) + Hb[5];
    float T  = (Hb[6] * gx + Hb[7] * gy) + Hb[8];

    // T = T + EPS * (1 - (|T| >= SMALL))
    if (!(fabsf(T) >= SMALL_F)) T = T + EPS_F;

    float xs = w0 / T;   // IEEE div, matches np
    float ys = w1 / T;

    float fx = floorf(xs);
    float fy = floorf(ys);
    int x0u = cvt_f32_i32_x86(fx);
    int y0u = cvt_f32_i32_x86(fy);

    int x1 = min(max(x0u + 1, 0), w - 1);
    int y1 = min(max(y0u + 1, 0), h - 1);
    int x0 = min(max(x0u, 0), w - 1);
    int y0 = min(max(y0u, 0), h - 1);

    float x0f = (float)x0, x1f = (float)x1;
    float y0f = (float)y0, y1f = (float)y1;

    float t1 = x1f - xs;   // (x1f - x)
    float t2 = y1f - ys;   // (y1f - y)
    float t3 = ys - y0f;   // (y - y0f)
    float t4 = xs - x0f;   // (x - x0f)

    float wa = t1 * t2;
    float wb = t1 * t3;
    float wc = t4 * t2;
    float wd = t4 * t3;

    const size_t plane = (size_t)h * (size_t)w;
    const float* sb = src + (size_t)b * 3u * plane;
    size_t i00 = (size_t)y0 * (size_t)w + (size_t)x0;  // Ia
    size_t i10 = (size_t)y1 * (size_t)w + (size_t)x0;  // Ib
    size_t i01 = (size_t)y0 * (size_t)w + (size_t)x1;  // Ic
    size_t i11 = (size_t)y1 * (size_t)w + (size_t)x1;  // Id

    size_t o = (size_t)b * 3u * plane + (size_t)y * (size_t)w + (size_t)x;

#pragma unroll
    for (int c = 0; c < 3; ++c) {
        const float* sc = sb + (size_t)c * plane;
        float Ia = sc[i00];
        float Ib = sc[i10];
        float Ic = sc[i01];
        float Id = sc[i11];
        // np order: (((wa*Ia + wb*Ib) + wc*Ic) + wd*Id), no FMA
        float r = ((wa * Ia + wb * Ib) + wc * Ic) + wd * Id;
        out[o + (size_t)c * plane] = r;
    }
}

extern "C" void kernel_launch(void* const* d_in, const int* in_sizes, int n_in,
                              void* d_out, int out_size, void* d_ws, size_t ws_size,
                              hipStream_t stream) {
    const float* src = (const float*)d_in[0];
    const float* Hm  = (const float*)d_in[1];
    float* out = (float*)d_out;

    const int B = in_sizes[1] / 9;          // 8
    const int C = 3;
    const size_t plane = (size_t)in_sizes[0] / ((size_t)B * C);
    const int h = 1024;                     // setup_inputs: 1024x1024
    const int w = (int)(plane / h);

    dim3 block(256, 1, 1);
    dim3 grid((w + 255) / 256, h, B);
    warp_bilinear_kernel<<<grid, block, 0, stream>>>(src, Hm, out, B, h, w);
}

// Round 2
// 185.993 us; speedup vs baseline: 1.2087x; 1.2087x over previous
//
#include <hip/hip_runtime.h>
#include <math.h>
#include <limits.h>
#include <string.h>

// Homography warp + bilinear sampling, bit-faithful to the numpy reference:
//  - no FMA contraction (pragma) so products/sums round like np
//  - two IEEE divisions (not reciprocal-multiply)
//  - float->int32 emulates x86 cvttss2si (overflow -> INT_MIN -> clips to 0)
//  - weight/accumulate expression order identical to the reference
//
// Perf structure (R1): gather-instruction-bound, so
//  - adjacent taps (x0, x1=x0+1 or clipped-equal) loaded as one 8B pair +
//    cndmask select (bit-exact; halves gather instr count 12 -> 6/px)
//  - PX=4 pixels/thread for load ILP / latency hiding
//  - nontemporal stores: 96 MB streaming output must not evict cached src

#define SMALL_F 1e-7f
#define EPS_F   1e-6f
#define PX 4

__device__ __forceinline__ int cvt_f32_i32_x86(float f) {
    // x86 cvttss2si: values >= 2^31 (incl. +inf) give INT_MIN.
    if (f >= 2147483648.0f) return INT_MIN;
    return (int)f;  // input is pre-floored, trunc == floor
}

__global__ void __launch_bounds__(256)
warp_bilinear_kernel(const float* __restrict__ src, const float* __restrict__ Hm,
                     float* __restrict__ out, int B, int h, int w) {
#pragma clang fp contract(off)
    const int y  = blockIdx.y;
    const int b  = blockIdx.z;
    const int tx = threadIdx.x;
    const int xstart = blockIdx.x * (256 * PX) + tx;

    const float* Hb = Hm + (size_t)b * 9;   // block-uniform -> s_load
    const float H0 = Hb[0], H1 = Hb[1], H2 = Hb[2];
    const float H3 = Hb[3], H4 = Hb[4], H5 = Hb[5];
    const float H6 = Hb[6], H7 = Hb[7], H8 = Hb[8];
    const float gy = (float)y;
    // Hoisting the *products* Hj*gy is bit-identical (single rounding each);
    // the sums below keep the reference's left-assoc, contraction-off order.
    const float p1 = H1 * gy, p4 = H4 * gy, p7 = H7 * gy;

    int   idx0[PX], idx1[PX];
    float wav[PX], wbv[PX], wcv[PX], wdv[PX];
    bool  sA[PX], sC[PX], valid[PX];

#pragma unroll
    for (int k = 0; k < PX; ++k) {
        int x = xstart + 256 * k;
        valid[k] = (x < w);
        float gx = (float)x;
        float w0 = (H0 * gx + p1) + H2;      // (H0*gx + H1*gy) + H2
        float w1 = (H3 * gx + p4) + H5;
        float T  = (H6 * gx + p7) + H8;
        if (!(fabsf(T) >= SMALL_F)) T = T + EPS_F;
        float xs = w0 / T;                   // IEEE div, matches np
        float ys = w1 / T;
        float fx = floorf(xs), fy = floorf(ys);
        int x0u = cvt_f32_i32_x86(fx);
        int y0u = cvt_f32_i32_x86(fy);
        int x1 = min(max(x0u + 1, 0), w - 1);
        int y1 = min(max(y0u + 1, 0), h - 1);
        int x0 = min(max(x0u, 0), w - 1);
        int y0 = min(max(y0u, 0), h - 1);
        float t1 = (float)x1 - xs;           // (x1f - x)
        float t2 = (float)y1 - ys;           // (y1f - y)
        float t3 = ys - (float)y0;           // (y - y0f)
        float t4 = xs - (float)x0;           // (x - x0f)
        wav[k] = t1 * t2;
        wbv[k] = t1 * t3;
        wcv[k] = t4 * t2;
        wdv[k] = t4 * t3;
        // Pair base: taps are {xb, xb+1} with x0,x1 each one of the two
        // (identical at clipped edges). Selects below are bit-exact.
        int xb = min(max(x0u, 0), w - 2);
        sA[k] = (x0 == xb);
        sC[k] = (x1 == xb);
        idx0[k] = y0 * w + xb;
        idx1[k] = y1 * w + xb;
    }

    const size_t plane = (size_t)h * (size_t)w;
    const float* sb = src + (size_t)b * 3 * plane;
    float* ob = out + (size_t)b * 3 * plane + (size_t)y * (size_t)w;

#pragma unroll
    for (int c = 0; c < 3; ++c) {
        const float* sc = sb + (size_t)c * plane;
        float* oc = ob + (size_t)c * plane;
#pragma unroll
        for (int k = 0; k < PX; ++k) {
            if (!valid[k]) continue;
            float pr0[2], pr1[2];
            // memcpy: alignment-safe; compiler emits the widest legal load
            // (dwordx2 w/ unaligned-access on gfx950, else 2x dword).
            __builtin_memcpy(pr0, sc + idx0[k], 8);
            __builtin_memcpy(pr1, sc + idx1[k], 8);
            float Ia = sA[k] ? pr0[0] : pr0[1];
            float Ic = sC[k] ? pr0[0] : pr0[1];
            float Ib = sA[k] ? pr1[0] : pr1[1];
            float Id = sC[k] ? pr1[0] : pr1[1];
            // np order: (((wa*Ia + wb*Ib) + wc*Ic) + wd*Id), no FMA
            float r = ((wav[k] * Ia + wbv[k] * Ib) + wcv[k] * Ic) + wdv[k] * Id;
            __builtin_nontemporal_store(r, oc + xstart + 256 * k);
        }
    }
}

extern "C" void kernel_launch(void* const* d_in, const int* in_sizes, int n_in,
                              void* d_out, int out_size, void* d_ws, size_t ws_size,
                              hipStream_t stream) {
    const float* src = (const float*)d_in[0];
    const float* Hm  = (const float*)d_in[1];
    float* out = (float*)d_out;

    const int B = in_sizes[1] / 9;          // 8
    const int C = 3;
    const size_t plane = (size_t)in_sizes[0] / ((size_t)B * C);
    const int h = 1024;                     // setup_inputs: 1024x1024
    const int w = (int)(plane / h);

    dim3 block(256, 1, 1);
    dim3 grid((w + 256 * PX - 1) / (256 * PX), h, B);
    warp_bilinear_kernel<<<grid, block, 0, stream>>>(src, Hm, out, B, h, w);
}